// Round 14
// baseline (702.299 us; speedup 1.0000x reference)
//
#include <hip/hip_runtime.h>

#define NN 100000
#define EE 1600000
#define HIDD 128
#define TGTT 64
#define GGG 512
#define NBK 98          // buckets of 1024 nodes
#define CAPB 17408      // bucket capacity: mean 16327 +8.5 sd
#define ABLK 200        // binA blocks, 8000 edges each
#define LSTR 136        // sX row stride (shorts)
#define CVTB 3125       // cvt blocks in prologue
#define GBLK 1563       // gmlp main blocks (64 nodes each)
#define PBLK 782        // projpool blocks (128 nodes each)
#define OUTB 128        // out filler blocks (4 graphs each @256 thr)

typedef unsigned short ushort_t;
typedef __attribute__((ext_vector_type(8))) short short8;
typedef __attribute__((ext_vector_type(4))) float f32x4;
typedef __attribute__((ext_vector_type(4))) unsigned short us4;

__device__ __forceinline__ float b2f(ushort_t u) {
    union { unsigned int i; float f; } v; v.i = ((unsigned int)u) << 16; return v.f;
}
__device__ __forceinline__ ushort_t f2b(float f) {
    union { float f; unsigned int i; } v; v.f = f;
    unsigned int r = (v.i + 0x7fffu + ((v.i >> 16) & 1u)) >> 16;
    return (ushort_t)r;
}

// ======================= prologue: cvt | weight-prep | goff | binA in one launch ============
__global__ __launch_bounds__(256) void k_pro(const float* __restrict__ x, ushort_t* __restrict__ Xb,
                                             const float* __restrict__ cw1, const float* __restrict__ cw2,
                                             const float* __restrict__ pw1, ushort_t* __restrict__ Wt,
                                             const int* __restrict__ batch, int* __restrict__ goff,
                                             const int* __restrict__ ei, int* __restrict__ gcnt,
                                             unsigned int* __restrict__ bbuf) {
    __shared__ ushort_t sW[128 * 129];
    __shared__ int cnt[NBK], base[NBK], cur[NBK];
    int b = blockIdx.x, t = threadIdx.x;

    if (b < CVTB) {
        long i0 = (long)b * 1024 + t;
#pragma unroll
        for (int c = 0; c < 4; c++) {
            long i = i0 + c * 256;
            float4 v = ((const float4*)x)[i];
            us4 o; o.x = f2b(v.x); o.y = f2b(v.y); o.z = f2b(v.z); o.w = f2b(v.w);
            ((us4*)Xb)[i] = o;
        }
        return;
    }
    b -= CVTB;
    if (b < 9) {
        int l = b / 3, j = b % 3;
        const float* src = (j == 0 ? cw1 : j == 1 ? cw2 : pw1) + (size_t)l * HIDD * HIDD;
        ushort_t* dst = Wt + (size_t)b * HIDD * HIDD;
        for (int i = t; i < HIDD * HIDD; i += 256) {
            int k = i >> 7, n = i & 127;
            sW[n * 129 + k] = f2b(src[i]);
        }
        __syncthreads();
        for (int i = t; i < HIDD * HIDD; i += 256) {
            dst[i] = sW[(i >> 7) * 129 + (i & 127)];
        }
        return;
    }
    b -= 9;
    if (b < 3) {
        int g = b * 256 + t;
        if (g > GGG) return;
        int lo = 0, hi = NN;
        while (lo < hi) { int mid = (lo + hi) >> 1; if (batch[mid] < g) lo = mid + 1; else hi = mid; }
        goff[g] = lo;
        return;
    }
    b -= 3;
    {
        if (t < NBK) cnt[t] = 0;
        __syncthreads();
        int e0 = b * 8000;
        int e1 = min(e0 + 8000, EE);
        for (int e = e0 + t; e < e1; e += 256)
            atomicAdd(&cnt[ei[EE + e] >> 10], 1);
        __syncthreads();
        if (t < NBK) { base[t] = atomicAdd(&gcnt[t], cnt[t]); cur[t] = 0; }
        __syncthreads();
        for (int e = e0 + t; e < e1; e += 256) {
            int s = ei[e], d = ei[EE + e];
            int bk = d >> 10;
            int off = base[bk] + atomicAdd(&cur[bk], 1);
            if (off < CAPB)
                bbuf[(long)bk * CAPB + off] = (unsigned int)s | (((unsigned int)d & 1023u) << 17);
        }
    }
}

// ======================= CSR phase B with inlined bucket-base scan =======================
__global__ __launch_bounds__(256) void k_csr(const int* __restrict__ gcnt,
                                             const unsigned int* __restrict__ bbuf,
                                             int* __restrict__ rowptr, int* __restrict__ csr) {
    __shared__ int ldeg[1024], lcur[1024], tsum[256], sb[NBK];
    int b = blockIdx.x, t = threadIdx.x;
    if (t < NBK) sb[t] = gcnt[t];
    __syncthreads();
    if (t == 0) { int a = 0; for (int i = 0; i < NBK; i++) { int v = sb[i]; sb[i] = a; a += v; } }
    __syncthreads();
    int cnt = min(gcnt[b], CAPB);
    int base = sb[b];
    const unsigned int* bb = bbuf + (long)b * CAPB;
#pragma unroll
    for (int i = 0; i < 4; i++) ldeg[t + 256 * i] = 0;
    __syncthreads();
    for (int i = t; i < cnt; i += 256) atomicAdd(&ldeg[bb[i] >> 17], 1);
    __syncthreads();
    int d0 = ldeg[4 * t], d1 = ldeg[4 * t + 1], d2 = ldeg[4 * t + 2], d3 = ldeg[4 * t + 3];
    int tot = d0 + d1 + d2 + d3;
    tsum[t] = tot;
    __syncthreads();
    for (int off = 1; off < 256; off <<= 1) {
        int u = (t >= off) ? tsum[t - off] : 0;
        __syncthreads();
        tsum[t] += u;
        __syncthreads();
    }
    int texcl = tsum[t] - tot;
    int p0 = base + texcl, p1 = p0 + d0, p2 = p1 + d1, p3 = p2 + d2;
    lcur[4 * t] = p0; lcur[4 * t + 1] = p1; lcur[4 * t + 2] = p2; lcur[4 * t + 3] = p3;
    int gnode = b * 1024 + 4 * t;
    if (gnode < NN)     rowptr[gnode]     = p0;
    if (gnode + 1 < NN) rowptr[gnode + 1] = p1;
    if (gnode + 2 < NN) rowptr[gnode + 2] = p2;
    if (gnode + 3 < NN) rowptr[gnode + 3] = p3;
    if (b == NBK - 1 && t == 0) rowptr[NN] = EE;
    __syncthreads();
    for (int i = t; i < cnt; i += 256) {
        unsigned int en = bb[i];
        int pos = atomicAdd(&lcur[en >> 17], 1);
        csr[pos] = (int)(en & 0x1FFFFu);
    }
}

// ======================= fused gather + 2-layer MLP: 256 thr, M=64 tile ==============
// sX = 17.4 KB -> 8 blocks/CU capacity; grid 1563 -> ~6 blocks/CU (24 waves) in one round
// during the latency-bound gather. Each wave's MLP touches only its own 16-row strip,
// so only ONE barrier (post-gather) is needed.
__global__ __launch_bounds__(256) void k_gmlp(const ushort_t* __restrict__ hin,
                                              const int* __restrict__ rowptr,
                                              const int* __restrict__ csr,
                                              const float* __restrict__ eps, int l,
                                              const ushort_t* __restrict__ Wt1, const float* __restrict__ B1,
                                              const ushort_t* __restrict__ Wt2, const float* __restrict__ B2,
                                              ushort_t* __restrict__ Y,
                                              const float* __restrict__ pooledP, const int* __restrict__ goff,
                                              const float* __restrict__ WoP, const float* __restrict__ BoP,
                                              float* __restrict__ outP, int lprev) {
    __shared__ ushort_t sX[64 * LSTR];
    int tid = threadIdx.x;

    if (blockIdx.x >= GBLK) {     // ---- filler: out[g] for previous layer (4 graphs/block)
        if (lprev < 0) return;
        int ob = blockIdx.x - GBLK;
        int sub = tid >> 6, tt = tid & 63;
        int g = ob * 4 + sub;
        if (g >= GGG) return;
        float cntg = (float)(goff[g + 1] - goff[g]);
        float acc = cntg * BoP[tt];
        const float* p = pooledP + (long)g * HIDD;
        for (int k = 0; k < HIDD; k++) acc += p[k] * WoP[k * TGTT + tt];
        outP[(long)g * (3 * TGTT) + lprev * TGTT + tt] = acc;
        return;
    }

    long base = (long)blockIdx.x * 64;
    int lane = tid & 15, ng = tid >> 4;     // 16 nodes per pass
    int off = lane << 3;
    float e1 = 1.0f + eps[l];

    // ---- gather phase: 4 passes x 16 nodes
#pragma unroll 1
    for (int it = 0; it < 4; it++) {
        int row = it * 16 + ng;
        long node = base + row;
        short8 o = (short8)0;
        if (node < NN) {
            short8 h = *(const short8*)(hin + (node << 7) + off);
            float acc[8];
#pragma unroll
            for (int t = 0; t < 8; t++) acc[t] = e1 * b2f((ushort_t)h[t]);
            int jb = rowptr[node], je = rowptr[node + 1];
            int j = jb;
            for (; j + 8 <= je; j += 8) {
                int s0 = csr[j], s1 = csr[j + 1], s2 = csr[j + 2], s3 = csr[j + 3];
                int s4 = csr[j + 4], s5 = csr[j + 5], s6 = csr[j + 6], s7 = csr[j + 7];
                short8 v0 = *(const short8*)(hin + ((long)s0 << 7) + off);
                short8 v1 = *(const short8*)(hin + ((long)s1 << 7) + off);
                short8 v2 = *(const short8*)(hin + ((long)s2 << 7) + off);
                short8 v3 = *(const short8*)(hin + ((long)s3 << 7) + off);
                short8 v4 = *(const short8*)(hin + ((long)s4 << 7) + off);
                short8 v5 = *(const short8*)(hin + ((long)s5 << 7) + off);
                short8 v6 = *(const short8*)(hin + ((long)s6 << 7) + off);
                short8 v7 = *(const short8*)(hin + ((long)s7 << 7) + off);
#pragma unroll
                for (int t = 0; t < 8; t++)
                    acc[t] += ((b2f((ushort_t)v0[t]) + b2f((ushort_t)v1[t])) +
                               (b2f((ushort_t)v2[t]) + b2f((ushort_t)v3[t]))) +
                              ((b2f((ushort_t)v4[t]) + b2f((ushort_t)v5[t])) +
                               (b2f((ushort_t)v6[t]) + b2f((ushort_t)v7[t])));
            }
            for (; j + 4 <= je; j += 4) {
                int s0 = csr[j], s1 = csr[j + 1], s2 = csr[j + 2], s3 = csr[j + 3];
                short8 v0 = *(const short8*)(hin + ((long)s0 << 7) + off);
                short8 v1 = *(const short8*)(hin + ((long)s1 << 7) + off);
                short8 v2 = *(const short8*)(hin + ((long)s2 << 7) + off);
                short8 v3 = *(const short8*)(hin + ((long)s3 << 7) + off);
#pragma unroll
                for (int t = 0; t < 8; t++)
                    acc[t] += (b2f((ushort_t)v0[t]) + b2f((ushort_t)v1[t])) +
                              (b2f((ushort_t)v2[t]) + b2f((ushort_t)v3[t]));
            }
            for (; j < je; j++) {
                int s = csr[j];
                short8 v = *(const short8*)(hin + ((long)s << 7) + off);
#pragma unroll
                for (int t = 0; t < 8; t++) acc[t] += b2f((ushort_t)v[t]);
            }
#pragma unroll
            for (int t = 0; t < 8; t++) o[t] = (short)f2b(acc[t]);
        }
        *(short8*)(sX + row * LSTR + off) = o;
    }
    __syncthreads();   // the only barrier: gather wrote rows across waves

    // ---- MLP: 4 waves x 1 private strip of 16 rows; weights from L2
    int w = tid >> 6, l64 = tid & 63, q = l64 >> 4, l16 = l64 & 15;
    int r0 = w * 16;
    short8 a[4];
#pragma unroll
    for (int c = 0; c < 4; c++)
        a[c] = *(const short8*)(sX + (r0 + l16) * LSTR + q * 8 + c * 32);
    f32x4 acc[8];
#pragma unroll
    for (int nt = 0; nt < 8; nt++) {
        int col = nt * 16 + l16;
        float bias = B1[col];
        f32x4 c0 = {bias, bias, bias, bias};
        const ushort_t* bB = Wt1 + col * HIDD + q * 8;
#pragma unroll
        for (int c = 0; c < 4; c++) {
            short8 b = *(const short8*)(bB + c * 32);
            c0 = __builtin_amdgcn_mfma_f32_16x16x32_bf16(a[c], b, c0, 0, 0, 0);
        }
        acc[nt] = c0;
    }
    // write T=relu(acc) into own strip (wave-private rows; no barrier needed)
#pragma unroll
    for (int nt = 0; nt < 8; nt++) {
        int col = nt * 16 + l16;
#pragma unroll
        for (int r = 0; r < 4; r++)
            sX[(r0 + q * 4 + r) * LSTR + col] = f2b(fmaxf(acc[nt][r], 0.f));
    }
    // GEMM2: T @ Wt2 + B2 -> Y (reads own strip only)
#pragma unroll
    for (int c = 0; c < 4; c++)
        a[c] = *(const short8*)(sX + (r0 + l16) * LSTR + q * 8 + c * 32);
#pragma unroll
    for (int nt = 0; nt < 8; nt++) {
        int col = nt * 16 + l16;
        float bias = B2[col];
        f32x4 c0 = {bias, bias, bias, bias};
        const ushort_t* bB = Wt2 + col * HIDD + q * 8;
#pragma unroll
        for (int c = 0; c < 4; c++) {
            short8 b = *(const short8*)(bB + c * 32);
            c0 = __builtin_amdgcn_mfma_f32_16x16x32_bf16(a[c], b, c0, 0, 0, 0);
        }
#pragma unroll
        for (int r = 0; r < 4; r++) {
            long row = base + r0 + q * 4 + r;
            if (row < NN) Y[(row << 7) + col] = f2b(c0[r]);
        }
    }
}

// ======================= GraphNorm stats (+ zero pooled for this layer) ==================
__global__ __launch_bounds__(512) void k_gstat(const ushort_t* __restrict__ Hraw,
                                               const int* __restrict__ goff,
                                               const float* __restrict__ scale,
                                               const float* __restrict__ weight,
                                               float* __restrict__ msb, float* __restrict__ invb,
                                               float* __restrict__ pooled) {
    int g = blockIdx.x;
    int s = goff[g], e = goff[g + 1];
    float cnt = (float)max(e - s, 1);
    int fp = threadIdx.x & 63;
    int r = threadIdx.x >> 6;
    int f0 = fp * 2;
    float s0 = 0.f, s1 = 0.f, q0 = 0.f, q1 = 0.f;
    for (int i = s + r; i < e; i += 8) {
        unsigned int v = *(const unsigned int*)(Hraw + ((long)i << 7) + f0);
        float a = b2f((ushort_t)(v & 0xffffu));
        float b = b2f((ushort_t)(v >> 16));
        s0 += a; q0 += a * a; s1 += b; q1 += b * b;
    }
    __shared__ float red[4][8][64];
    red[0][r][fp] = s0; red[1][r][fp] = q0; red[2][r][fp] = s1; red[3][r][fp] = q1;
    __syncthreads();
    if (r == 0) {
#pragma unroll
        for (int k = 1; k < 8; k++) {
            s0 += red[0][k][fp]; q0 += red[1][k][fp];
            s1 += red[2][k][fp]; q1 += red[3][k][fp];
        }
        float mean0 = s0 / cnt, mean1 = s1 / cnt;
        float ms0 = mean0 * scale[f0], ms1 = mean1 * scale[f0 + 1];
        float var0 = q0 / cnt - 2.f * ms0 * mean0 + ms0 * ms0;
        float var1 = q1 / cnt - 2.f * ms1 * mean1 + ms1 * ms1;
        msb[g * HIDD + f0] = ms0;
        msb[g * HIDD + f0 + 1] = ms1;
        invb[g * HIDD + f0] = weight[f0] / sqrtf(var0 + 1e-8f);
        invb[g * HIDD + f0 + 1] = weight[f0 + 1] / sqrtf(var1 + 1e-8f);
        pooled[g * HIDD + f0] = 0.f;
        pooled[g * HIDD + f0 + 1] = 0.f;
    }
}

// ======================= fused norm-apply + projection GEMM + pooling (R9 form) ============
__global__ __launch_bounds__(256) void k_projpool(const ushort_t* __restrict__ Hraw,
                                                  const int* __restrict__ batch,
                                                  const float* __restrict__ msb, const float* __restrict__ invb,
                                                  const float* __restrict__ gnb,
                                                  const ushort_t* __restrict__ Wt, const float* __restrict__ B,
                                                  ushort_t* __restrict__ Hn, float* __restrict__ pooled,
                                                  int store_hn) {
    __shared__ ushort_t sX[128 * LSTR];
    __shared__ int sgid[128];
    int tid = threadIdx.x;
    long base = (long)blockIdx.x * 128;
#pragma unroll
    for (int c = 0; c < 8; c++) {
        int idx = c * 256 + tid;
        int row = idx >> 4, cw = idx & 15;
        long grow = base + row;
        short8 v = (short8)0;
        if (grow < NN) {
            short8 raw = *(const short8*)(Hraw + (grow << 7) + (cw << 3));
            int g = batch[grow];
            if (cw == 0) sgid[row] = g;
            const float* msp = msb + g * HIDD + (cw << 3);
            const float* ivp = invb + g * HIDD + (cw << 3);
            const float* gbp = gnb + (cw << 3);
            float4 m0 = *(const float4*)msp, m1 = *(const float4*)(msp + 4);
            float4 i0 = *(const float4*)ivp, i1 = *(const float4*)(ivp + 4);
            float4 g0 = *(const float4*)gbp, g1 = *(const float4*)(gbp + 4);
            float mv[8] = {m0.x, m0.y, m0.z, m0.w, m1.x, m1.y, m1.z, m1.w};
            float iv[8] = {i0.x, i0.y, i0.z, i0.w, i1.x, i1.y, i1.z, i1.w};
            float gv[8] = {g0.x, g0.y, g0.z, g0.w, g1.x, g1.y, g1.z, g1.w};
#pragma unroll
            for (int t = 0; t < 8; t++) {
                float val = (b2f((ushort_t)raw[t]) - mv[t]) * iv[t] + gv[t];
                v[t] = (short)f2b(val > 0.f ? val : 0.f);
            }
            if (store_hn) *(short8*)(Hn + (grow << 7) + (cw << 3)) = v;
        } else if (cw == 0) {
            sgid[row] = -1;
        }
        *(short8*)(sX + row * LSTR + (cw << 3)) = v;
    }
    __syncthreads();

    int w = tid >> 6, l64 = tid & 63, q = l64 >> 4, l16 = l64 & 15;
    int r0 = w * 16, r1 = 64 + w * 16;
    short8 a0[4], a1[4];
#pragma unroll
    for (int c = 0; c < 4; c++) {
        a0[c] = *(const short8*)(sX + (r0 + l16) * LSTR + q * 8 + c * 32);
        a1[c] = *(const short8*)(sX + (r1 + l16) * LSTR + q * 8 + c * 32);
    }
    f32x4 acc0[8], acc1[8];
#pragma unroll
    for (int nt = 0; nt < 8; nt++) {
        int col = nt * 16 + l16;
        float bias = B[col];
        f32x4 c0 = {bias, bias, bias, bias};
        f32x4 c1 = c0;
        const ushort_t* bB = Wt + col * HIDD + q * 8;
#pragma unroll
        for (int c = 0; c < 4; c++) {
            short8 b = *(const short8*)(bB + c * 32);
            c0 = __builtin_amdgcn_mfma_f32_16x16x32_bf16(a0[c], b, c0, 0, 0, 0);
            c1 = __builtin_amdgcn_mfma_f32_16x16x32_bf16(a1[c], b, c1, 0, 0, 0);
        }
        acc0[nt] = c0; acc1[nt] = c1;
    }
    __syncthreads();
#pragma unroll
    for (int nt = 0; nt < 8; nt++) {
        int col = nt * 16 + l16;
#pragma unroll
        for (int r = 0; r < 4; r++) {
            sX[(r0 + q * 4 + r) * LSTR + col] = f2b(fmaxf(acc0[nt][r], 0.f));
            sX[(r1 + q * 4 + r) * LSTR + col] = f2b(fmaxf(acc1[nt][r], 0.f));
        }
    }
    __syncthreads();

    int f = tid & 127, half = tid >> 7;
    int rbeg = half * 64, rend = rbeg + 64;
    float sum = 0.f;
    int curg = -1;
    for (int row = rbeg; row < rend; row++) {
        int g = sgid[row];
        if (g != curg) {
            if (curg >= 0) atomicAdd(&pooled[(long)curg * HIDD + f], sum);
            sum = 0.f; curg = g;
        }
        if (g >= 0) sum += b2f(sX[row * LSTR + f]);
    }
    if (curg >= 0) atomicAdd(&pooled[(long)curg * HIDD + f], sum);
}

// ---- final out (layer 2): 4 graphs per 256-thread block
__global__ __launch_bounds__(256) void k_out(const float* __restrict__ pooled, const int* __restrict__ goff,
                                             const float* __restrict__ W, const float* __restrict__ B,
                                             float* __restrict__ out, int l) {
    int sub = threadIdx.x >> 6, tt = threadIdx.x & 63;
    int g = blockIdx.x * 4 + sub;
    if (g >= GGG) return;
    float cnt = (float)(goff[g + 1] - goff[g]);
    float acc = cnt * B[tt];
    const float* p = pooled + (long)g * HIDD;
    for (int k = 0; k < HIDD; k++) acc += p[k] * W[k * TGTT + tt];
    out[(long)g * (3 * TGTT) + l * TGTT + tt] = acc;
}

extern "C" void kernel_launch(void* const* d_in, const int* in_sizes, int n_in,
                              void* d_out, int out_size, void* d_ws, size_t ws_size,
                              hipStream_t stream) {
    const float* x    = (const float*)d_in[0];
    const int*   ei   = (const int*)d_in[1];
    const int*   batch= (const int*)d_in[2];
    const float* cw1  = (const float*)d_in[3];
    const float* cb1  = (const float*)d_in[4];
    const float* cw2  = (const float*)d_in[5];
    const float* cb2  = (const float*)d_in[6];
    const float* eps  = (const float*)d_in[7];
    const float* gsc  = (const float*)d_in[8];
    const float* gw   = (const float*)d_in[9];
    const float* gb   = (const float*)d_in[10];
    const float* pw1  = (const float*)d_in[11];
    const float* pb1  = (const float*)d_in[12];
    const float* pw2  = (const float*)d_in[13];
    const float* pb2  = (const float*)d_in[14];
    float* out = (float*)d_out;

    ushort_t* Xb   = (ushort_t*)d_ws;                       // N*128 bf16 — aliases Hn
    ushort_t* Hn   = Xb;
    ushort_t* Hraw = Xb + (size_t)NN * HIDD;                // N*128 bf16
    ushort_t* Wt   = Hraw + (size_t)NN * HIDD;              // 9*128*128 bf16
    float* msb     = (float*)(Wt + (size_t)9 * HIDD * HIDD);// G*128 f32
    float* invb    = msb + (size_t)GGG * HIDD;              // G*128 f32
    float* pooled  = invb + (size_t)GGG * HIDD;             // G*128 f32
    int* goff   = (int*)(pooled + (size_t)GGG * HIDD);      // G+1
    int* rowptr = goff + (GGG + 1);                         // N+1
    int* gcnt   = rowptr + (NN + 1);                        // NBK
    int* csr    = gcnt + NBK;                               // E
    unsigned int* bbuf = (unsigned int*)(csr + EE);         // NBK*CAPB

    hipMemsetAsync(gcnt, 0, NBK * sizeof(int), stream);
    k_pro<<<CVTB + 9 + 3 + ABLK, 256, 0, stream>>>(x, Xb, cw1, cw2, pw1, Wt, batch, goff, ei, gcnt, bbuf);
    k_csr<<<NBK, 256, 0, stream>>>(gcnt, bbuf, rowptr, csr);

    for (int l = 0; l < 3; l++) {
        const ushort_t* hin = (l == 0) ? Xb : Hn;
        ushort_t* Wt1 = Wt + (size_t)(l * 3 + 0) * HIDD * HIDD;
        ushort_t* Wt2 = Wt + (size_t)(l * 3 + 1) * HIDD * HIDD;
        ushort_t* Wtp = Wt + (size_t)(l * 3 + 2) * HIDD * HIDD;
        int grid = GBLK + (l > 0 ? OUTB : 0);
        k_gmlp<<<grid, 256, 0, stream>>>(hin, rowptr, csr, eps, l,
                                         Wt1, cb1 + l * HIDD, Wt2, cb2 + l * HIDD, Hraw,
                                         pooled, goff,
                                         pw2 + (size_t)(l - 1) * HIDD * TGTT, pb2 + (l - 1) * TGTT,
                                         out, l - 1);
        k_gstat<<<GGG, 512, 0, stream>>>(Hraw, goff, gsc + l * HIDD, gw + l * HIDD, msb, invb, pooled);
        k_projpool<<<PBLK, 256, 0, stream>>>(Hraw, batch, msb, invb, gb + l * HIDD,
                                             Wtp, pb1 + l * HIDD, Hn, pooled, (l < 2) ? 1 : 0);
    }
    k_out<<<OUTB, 256, 0, stream>>>(pooled, goff, pw2 + (size_t)2 * HIDD * TGTT, pb2 + 2 * TGTT, out, 2);
}

// Round 15
// 604.145 us; speedup vs baseline: 1.1625x; 1.1625x over previous
//
#include <hip/hip_runtime.h>

#define NN 100000
#define EE 1600000
#define HIDD 128
#define TGTT 64
#define GGG 512
#define NBK 98          // buckets of 1024 nodes
#define CAPB 17408      // bucket capacity: mean 16327 +8.5 sd
#define ABLK 200        // binA blocks, 8000 edges each
#define LSTR 136        // sX row stride (shorts)
#define CVTB 3125       // cvt blocks in prologue
#define GBLK 782        // gmlp/projpool main blocks
#define OUTB 128        // out filler blocks (4 graphs each @256 thr)

typedef unsigned short ushort_t;
typedef __attribute__((ext_vector_type(8))) short short8;
typedef __attribute__((ext_vector_type(4))) float f32x4;
typedef __attribute__((ext_vector_type(4))) unsigned short us4;

__device__ __forceinline__ float b2f(ushort_t u) {
    union { unsigned int i; float f; } v; v.i = ((unsigned int)u) << 16; return v.f;
}
__device__ __forceinline__ ushort_t f2b(float f) {
    union { float f; unsigned int i; } v; v.f = f;
    unsigned int r = (v.i + 0x7fffu + ((v.i >> 16) & 1u)) >> 16;
    return (ushort_t)r;
}

// ======================= prologue: cvt | weight-prep | goff | binA in one launch ============
__global__ __launch_bounds__(256) void k_pro(const float* __restrict__ x, ushort_t* __restrict__ Xb,
                                             const float* __restrict__ cw1, const float* __restrict__ cw2,
                                             const float* __restrict__ pw1, ushort_t* __restrict__ Wt,
                                             const int* __restrict__ batch, int* __restrict__ goff,
                                             const int* __restrict__ ei, int* __restrict__ gcnt,
                                             unsigned int* __restrict__ bbuf) {
    __shared__ ushort_t sW[128 * 129];
    __shared__ int cnt[NBK], base[NBK], cur[NBK];
    int b = blockIdx.x, t = threadIdx.x;

    if (b < CVTB) {
        long i0 = (long)b * 1024 + t;
#pragma unroll
        for (int c = 0; c < 4; c++) {
            long i = i0 + c * 256;
            float4 v = ((const float4*)x)[i];
            us4 o; o.x = f2b(v.x); o.y = f2b(v.y); o.z = f2b(v.z); o.w = f2b(v.w);
            ((us4*)Xb)[i] = o;
        }
        return;
    }
    b -= CVTB;
    if (b < 9) {
        int l = b / 3, j = b % 3;
        const float* src = (j == 0 ? cw1 : j == 1 ? cw2 : pw1) + (size_t)l * HIDD * HIDD;
        ushort_t* dst = Wt + (size_t)b * HIDD * HIDD;
        for (int i = t; i < HIDD * HIDD; i += 256) {
            int k = i >> 7, n = i & 127;
            sW[n * 129 + k] = f2b(src[i]);
        }
        __syncthreads();
        for (int i = t; i < HIDD * HIDD; i += 256) {
            dst[i] = sW[(i >> 7) * 129 + (i & 127)];
        }
        return;
    }
    b -= 9;
    if (b < 3) {
        int g = b * 256 + t;
        if (g > GGG) return;
        int lo = 0, hi = NN;
        while (lo < hi) { int mid = (lo + hi) >> 1; if (batch[mid] < g) lo = mid + 1; else hi = mid; }
        goff[g] = lo;
        return;
    }
    b -= 3;
    {
        if (t < NBK) cnt[t] = 0;
        __syncthreads();
        int e0 = b * 8000;
        int e1 = min(e0 + 8000, EE);
        for (int e = e0 + t; e < e1; e += 256)
            atomicAdd(&cnt[ei[EE + e] >> 10], 1);
        __syncthreads();
        if (t < NBK) { base[t] = atomicAdd(&gcnt[t], cnt[t]); cur[t] = 0; }
        __syncthreads();
        for (int e = e0 + t; e < e1; e += 256) {
            int s = ei[e], d = ei[EE + e];
            int bk = d >> 10;
            int off = base[bk] + atomicAdd(&cur[bk], 1);
            if (off < CAPB)
                bbuf[(long)bk * CAPB + off] = (unsigned int)s | (((unsigned int)d & 1023u) << 17);
        }
    }
}

// ======================= CSR phase B with inlined bucket-base scan =======================
__global__ __launch_bounds__(256) void k_csr(const int* __restrict__ gcnt,
                                             const unsigned int* __restrict__ bbuf,
                                             int* __restrict__ rowptr, int* __restrict__ csr) {
    __shared__ int ldeg[1024], lcur[1024], tsum[256], sb[NBK];
    int b = blockIdx.x, t = threadIdx.x;
    if (t < NBK) sb[t] = gcnt[t];
    __syncthreads();
    if (t == 0) { int a = 0; for (int i = 0; i < NBK; i++) { int v = sb[i]; sb[i] = a; a += v; } }
    __syncthreads();
    int cnt = min(gcnt[b], CAPB);
    int base = sb[b];
    const unsigned int* bb = bbuf + (long)b * CAPB;
#pragma unroll
    for (int i = 0; i < 4; i++) ldeg[t + 256 * i] = 0;
    __syncthreads();
    for (int i = t; i < cnt; i += 256) atomicAdd(&ldeg[bb[i] >> 17], 1);
    __syncthreads();
    int d0 = ldeg[4 * t], d1 = ldeg[4 * t + 1], d2 = ldeg[4 * t + 2], d3 = ldeg[4 * t + 3];
    int tot = d0 + d1 + d2 + d3;
    tsum[t] = tot;
    __syncthreads();
    for (int off = 1; off < 256; off <<= 1) {
        int u = (t >= off) ? tsum[t - off] : 0;
        __syncthreads();
        tsum[t] += u;
        __syncthreads();
    }
    int texcl = tsum[t] - tot;
    int p0 = base + texcl, p1 = p0 + d0, p2 = p1 + d1, p3 = p2 + d2;
    lcur[4 * t] = p0; lcur[4 * t + 1] = p1; lcur[4 * t + 2] = p2; lcur[4 * t + 3] = p3;
    int gnode = b * 1024 + 4 * t;
    if (gnode < NN)     rowptr[gnode]     = p0;
    if (gnode + 1 < NN) rowptr[gnode + 1] = p1;
    if (gnode + 2 < NN) rowptr[gnode + 2] = p2;
    if (gnode + 3 < NN) rowptr[gnode + 3] = p3;
    if (b == NBK - 1 && t == 0) rowptr[NN] = EE;
    __syncthreads();
    for (int i = t; i < cnt; i += 256) {
        unsigned int en = bb[i];
        int pos = atomicAdd(&lcur[en >> 17], 1);
        csr[pos] = (int)(en & 0x1FFFFu);
    }
}

// ======================= fused gather + 2-layer MLP (R9 config, fewer barriers) =====
// M=128, 256 thr. After the post-gather barrier every wave touches only its own two
// 16-row strips, so NO intra-MLP barriers are needed.
__global__ __launch_bounds__(256) void k_gmlp(const ushort_t* __restrict__ hin,
                                              const int* __restrict__ rowptr,
                                              const int* __restrict__ csr,
                                              const float* __restrict__ eps, int l,
                                              const ushort_t* __restrict__ Wt1, const float* __restrict__ B1,
                                              const ushort_t* __restrict__ Wt2, const float* __restrict__ B2,
                                              ushort_t* __restrict__ Y,
                                              const float* __restrict__ pooledP, const int* __restrict__ goff,
                                              const float* __restrict__ WoP, const float* __restrict__ BoP,
                                              float* __restrict__ outP, int lprev) {
    __shared__ ushort_t sX[128 * LSTR];
    int tid = threadIdx.x;

    if (blockIdx.x >= GBLK) {     // ---- filler: out[g] for previous layer (4 graphs/block)
        if (lprev < 0) return;
        int ob = blockIdx.x - GBLK;
        int sub = tid >> 6, tt = tid & 63;
        int g = ob * 4 + sub;
        if (g >= GGG) return;
        float cntg = (float)(goff[g + 1] - goff[g]);
        float acc = cntg * BoP[tt];
        const float* p = pooledP + (long)g * HIDD;
        for (int k = 0; k < HIDD; k++) acc += p[k] * WoP[k * TGTT + tt];
        outP[(long)g * (3 * TGTT) + lprev * TGTT + tt] = acc;
        return;
    }

    long base = (long)blockIdx.x * 128;
    int lane = tid & 15, ng = tid >> 4;
    int off = lane << 3;
    float e1 = 1.0f + eps[l];

    // ---- gather phase: 8 passes x 16 nodes
#pragma unroll 1
    for (int it = 0; it < 8; it++) {
        int row = it * 16 + ng;
        long node = base + row;
        short8 o = (short8)0;
        if (node < NN) {
            short8 h = *(const short8*)(hin + (node << 7) + off);
            float acc[8];
#pragma unroll
            for (int t = 0; t < 8; t++) acc[t] = e1 * b2f((ushort_t)h[t]);
            int jb = rowptr[node], je = rowptr[node + 1];
            int j = jb;
            for (; j + 8 <= je; j += 8) {
                int s0 = csr[j], s1 = csr[j + 1], s2 = csr[j + 2], s3 = csr[j + 3];
                int s4 = csr[j + 4], s5 = csr[j + 5], s6 = csr[j + 6], s7 = csr[j + 7];
                short8 v0 = *(const short8*)(hin + ((long)s0 << 7) + off);
                short8 v1 = *(const short8*)(hin + ((long)s1 << 7) + off);
                short8 v2 = *(const short8*)(hin + ((long)s2 << 7) + off);
                short8 v3 = *(const short8*)(hin + ((long)s3 << 7) + off);
                short8 v4 = *(const short8*)(hin + ((long)s4 << 7) + off);
                short8 v5 = *(const short8*)(hin + ((long)s5 << 7) + off);
                short8 v6 = *(const short8*)(hin + ((long)s6 << 7) + off);
                short8 v7 = *(const short8*)(hin + ((long)s7 << 7) + off);
#pragma unroll
                for (int t = 0; t < 8; t++)
                    acc[t] += ((b2f((ushort_t)v0[t]) + b2f((ushort_t)v1[t])) +
                               (b2f((ushort_t)v2[t]) + b2f((ushort_t)v3[t]))) +
                              ((b2f((ushort_t)v4[t]) + b2f((ushort_t)v5[t])) +
                               (b2f((ushort_t)v6[t]) + b2f((ushort_t)v7[t])));
            }
            for (; j + 4 <= je; j += 4) {
                int s0 = csr[j], s1 = csr[j + 1], s2 = csr[j + 2], s3 = csr[j + 3];
                short8 v0 = *(const short8*)(hin + ((long)s0 << 7) + off);
                short8 v1 = *(const short8*)(hin + ((long)s1 << 7) + off);
                short8 v2 = *(const short8*)(hin + ((long)s2 << 7) + off);
                short8 v3 = *(const short8*)(hin + ((long)s3 << 7) + off);
#pragma unroll
                for (int t = 0; t < 8; t++)
                    acc[t] += (b2f((ushort_t)v0[t]) + b2f((ushort_t)v1[t])) +
                              (b2f((ushort_t)v2[t]) + b2f((ushort_t)v3[t]));
            }
            for (; j < je; j++) {
                int s = csr[j];
                short8 v = *(const short8*)(hin + ((long)s << 7) + off);
#pragma unroll
                for (int t = 0; t < 8; t++) acc[t] += b2f((ushort_t)v[t]);
            }
#pragma unroll
            for (int t = 0; t < 8; t++) o[t] = (short)f2b(acc[t]);
        }
        *(short8*)(sX + row * LSTR + off) = o;
    }
    __syncthreads();   // the only barrier: gather rows cross waves

    // ---- MLP: 4 waves x 2 private strips; no further barriers
    int w = tid >> 6, l64 = tid & 63, q = l64 >> 4, l16 = l64 & 15;
    int r0 = w * 16, r1 = 64 + w * 16;
    short8 a0[4], a1[4];
#pragma unroll
    for (int c = 0; c < 4; c++) {
        a0[c] = *(const short8*)(sX + (r0 + l16) * LSTR + q * 8 + c * 32);
        a1[c] = *(const short8*)(sX + (r1 + l16) * LSTR + q * 8 + c * 32);
    }
    f32x4 acc0[8], acc1[8];
#pragma unroll
    for (int nt = 0; nt < 8; nt++) {
        int col = nt * 16 + l16;
        float bias = B1[col];
        f32x4 c0 = {bias, bias, bias, bias};
        f32x4 c1 = c0;
        const ushort_t* bB = Wt1 + col * HIDD + q * 8;
#pragma unroll
        for (int c = 0; c < 4; c++) {
            short8 b = *(const short8*)(bB + c * 32);
            c0 = __builtin_amdgcn_mfma_f32_16x16x32_bf16(a0[c], b, c0, 0, 0, 0);
            c1 = __builtin_amdgcn_mfma_f32_16x16x32_bf16(a1[c], b, c1, 0, 0, 0);
        }
        acc0[nt] = c0; acc1[nt] = c1;
    }
    // T = relu(acc) -> own strips (wave-private)
#pragma unroll
    for (int nt = 0; nt < 8; nt++) {
        int col = nt * 16 + l16;
#pragma unroll
        for (int r = 0; r < 4; r++) {
            sX[(r0 + q * 4 + r) * LSTR + col] = f2b(fmaxf(acc0[nt][r], 0.f));
            sX[(r1 + q * 4 + r) * LSTR + col] = f2b(fmaxf(acc1[nt][r], 0.f));
        }
    }
    // GEMM2: T @ Wt2 + B2 -> Y (reads own strips)
#pragma unroll
    for (int c = 0; c < 4; c++) {
        a0[c] = *(const short8*)(sX + (r0 + l16) * LSTR + q * 8 + c * 32);
        a1[c] = *(const short8*)(sX + (r1 + l16) * LSTR + q * 8 + c * 32);
    }
#pragma unroll
    for (int nt = 0; nt < 8; nt++) {
        int col = nt * 16 + l16;
        float bias = B2[col];
        f32x4 c0 = {bias, bias, bias, bias};
        f32x4 c1 = c0;
        const ushort_t* bB = Wt2 + col * HIDD + q * 8;
#pragma unroll
        for (int c = 0; c < 4; c++) {
            short8 b = *(const short8*)(bB + c * 32);
            c0 = __builtin_amdgcn_mfma_f32_16x16x32_bf16(a0[c], b, c0, 0, 0, 0);
            c1 = __builtin_amdgcn_mfma_f32_16x16x32_bf16(a1[c], b, c1, 0, 0, 0);
        }
#pragma unroll
        for (int r = 0; r < 4; r++) {
            long row0 = base + r0 + q * 4 + r;
            long row1 = base + r1 + q * 4 + r;
            if (row0 < NN) Y[(row0 << 7) + col] = f2b(c0[r]);
            if (row1 < NN) Y[(row1 << 7) + col] = f2b(c1[r]);
        }
    }
}

// ======================= GraphNorm stats, vectorized short8 loads ==================
__global__ __launch_bounds__(512) void k_gstat(const ushort_t* __restrict__ Hraw,
                                               const int* __restrict__ goff,
                                               const float* __restrict__ scale,
                                               const float* __restrict__ weight,
                                               float* __restrict__ msb, float* __restrict__ invb,
                                               float* __restrict__ pooled) {
    __shared__ float red[2][32][128];
    int g = blockIdx.x;
    int s = goff[g], e = goff[g + 1];
    float cnt = (float)max(e - s, 1);
    int lane = threadIdx.x & 15;   // 8-feature group
    int rg = threadIdx.x >> 4;     // 0..31 row groups
    int f0 = lane << 3;
    float sum[8], sq[8];
#pragma unroll
    for (int t = 0; t < 8; t++) { sum[t] = 0.f; sq[t] = 0.f; }
    for (int i = s + rg; i < e; i += 32) {
        short8 v = *(const short8*)(Hraw + ((long)i << 7) + f0);
#pragma unroll
        for (int t = 0; t < 8; t++) { float a = b2f((ushort_t)v[t]); sum[t] += a; sq[t] += a * a; }
    }
#pragma unroll
    for (int t = 0; t < 8; t++) { red[0][rg][f0 + t] = sum[t]; red[1][rg][f0 + t] = sq[t]; }
    __syncthreads();
    for (int off = 16; off > 0; off >>= 1) {
        if (rg < off) {
#pragma unroll
            for (int t = 0; t < 8; t++) {
                red[0][rg][f0 + t] += red[0][rg + off][f0 + t];
                red[1][rg][f0 + t] += red[1][rg + off][f0 + t];
            }
        }
        __syncthreads();
    }
    if (rg == 0) {
#pragma unroll
        for (int t = 0; t < 8; t++) {
            int f = f0 + t;
            float mean = red[0][0][f] / cnt;
            float ms = mean * scale[f];
            float var = red[1][0][f] / cnt - 2.f * ms * mean + ms * ms;
            msb[g * HIDD + f] = ms;
            invb[g * HIDD + f] = weight[f] / sqrtf(var + 1e-8f);
            pooled[g * HIDD + f] = 0.f;
        }
    }
}

// ======================= fused norm-apply + projection GEMM + pooling ============
__global__ __launch_bounds__(256) void k_projpool(const ushort_t* __restrict__ Hraw,
                                                  const int* __restrict__ batch,
                                                  const float* __restrict__ msb, const float* __restrict__ invb,
                                                  const float* __restrict__ gnb,
                                                  const ushort_t* __restrict__ Wt, const float* __restrict__ B,
                                                  ushort_t* __restrict__ Hn, float* __restrict__ pooled,
                                                  int store_hn) {
    __shared__ ushort_t sX[128 * LSTR];
    __shared__ int sgid[128];
    int tid = threadIdx.x;
    long base = (long)blockIdx.x * 128;
#pragma unroll
    for (int c = 0; c < 8; c++) {
        int idx = c * 256 + tid;
        int row = idx >> 4, cw = idx & 15;
        long grow = base + row;
        short8 v = (short8)0;
        if (grow < NN) {
            short8 raw = *(const short8*)(Hraw + (grow << 7) + (cw << 3));
            int g = batch[grow];
            if (cw == 0) sgid[row] = g;
            const float* msp = msb + g * HIDD + (cw << 3);
            const float* ivp = invb + g * HIDD + (cw << 3);
            const float* gbp = gnb + (cw << 3);
            float4 m0 = *(const float4*)msp, m1 = *(const float4*)(msp + 4);
            float4 i0 = *(const float4*)ivp, i1 = *(const float4*)(ivp + 4);
            float4 g0 = *(const float4*)gbp, g1 = *(const float4*)(gbp + 4);
            float mv[8] = {m0.x, m0.y, m0.z, m0.w, m1.x, m1.y, m1.z, m1.w};
            float iv[8] = {i0.x, i0.y, i0.z, i0.w, i1.x, i1.y, i1.z, i1.w};
            float gv[8] = {g0.x, g0.y, g0.z, g0.w, g1.x, g1.y, g1.z, g1.w};
#pragma unroll
            for (int t = 0; t < 8; t++) {
                float val = (b2f((ushort_t)raw[t]) - mv[t]) * iv[t] + gv[t];
                v[t] = (short)f2b(val > 0.f ? val : 0.f);
            }
            if (store_hn) *(short8*)(Hn + (grow << 7) + (cw << 3)) = v;
        } else if (cw == 0) {
            sgid[row] = -1;
        }
        *(short8*)(sX + row * LSTR + (cw << 3)) = v;
    }
    __syncthreads();   // staging wrote rows across waves

    int w = tid >> 6, l64 = tid & 63, q = l64 >> 4, l16 = l64 & 15;
    int r0 = w * 16, r1 = 64 + w * 16;
    short8 a0[4], a1[4];
#pragma unroll
    for (int c = 0; c < 4; c++) {
        a0[c] = *(const short8*)(sX + (r0 + l16) * LSTR + q * 8 + c * 32);
        a1[c] = *(const short8*)(sX + (r1 + l16) * LSTR + q * 8 + c * 32);
    }
    f32x4 acc0[8], acc1[8];
#pragma unroll
    for (int nt = 0; nt < 8; nt++) {
        int col = nt * 16 + l16;
        float bias = B[col];
        f32x4 c0 = {bias, bias, bias, bias};
        f32x4 c1 = c0;
        const ushort_t* bB = Wt + col * HIDD + q * 8;
#pragma unroll
        for (int c = 0; c < 4; c++) {
            short8 b = *(const short8*)(bB + c * 32);
            c0 = __builtin_amdgcn_mfma_f32_16x16x32_bf16(a0[c], b, c0, 0, 0, 0);
            c1 = __builtin_amdgcn_mfma_f32_16x16x32_bf16(a1[c], b, c1, 0, 0, 0);
        }
        acc0[nt] = c0; acc1[nt] = c1;
    }
    // z = relu(acc) -> own strips (wave-private; no barrier before this)
#pragma unroll
    for (int nt = 0; nt < 8; nt++) {
        int col = nt * 16 + l16;
#pragma unroll
        for (int r = 0; r < 4; r++) {
            sX[(r0 + q * 4 + r) * LSTR + col] = f2b(fmaxf(acc0[nt][r], 0.f));
            sX[(r1 + q * 4 + r) * LSTR + col] = f2b(fmaxf(acc1[nt][r], 0.f));
        }
    }
    __syncthreads();   // pooling reads all rows

    int f = tid & 127, half = tid >> 7;
    int rbeg = half * 64, rend = rbeg + 64;
    float sum = 0.f;
    int curg = -1;
    for (int row = rbeg; row < rend; row++) {
        int g = sgid[row];
        if (g != curg) {
            if (curg >= 0) atomicAdd(&pooled[(long)curg * HIDD + f], sum);
            sum = 0.f; curg = g;
        }
        if (g >= 0) sum += b2f(sX[row * LSTR + f]);
    }
    if (curg >= 0) atomicAdd(&pooled[(long)curg * HIDD + f], sum);
}

// ---- final out (layer 2): 4 graphs per 256-thread block
__global__ __launch_bounds__(256) void k_out(const float* __restrict__ pooled, const int* __restrict__ goff,
                                             const float* __restrict__ W, const float* __restrict__ B,
                                             float* __restrict__ out, int l) {
    int sub = threadIdx.x >> 6, tt = threadIdx.x & 63;
    int g = blockIdx.x * 4 + sub;
    if (g >= GGG) return;
    float cnt = (float)(goff[g + 1] - goff[g]);
    float acc = cnt * B[tt];
    const float* p = pooled + (long)g * HIDD;
    for (int k = 0; k < HIDD; k++) acc += p[k] * W[k * TGTT + tt];
    out[(long)g * (3 * TGTT) + l * TGTT + tt] = acc;
}

extern "C" void kernel_launch(void* const* d_in, const int* in_sizes, int n_in,
                              void* d_out, int out_size, void* d_ws, size_t ws_size,
                              hipStream_t stream) {
    const float* x    = (const float*)d_in[0];
    const int*   ei   = (const int*)d_in[1];
    const int*   batch= (const int*)d_in[2];
    const float* cw1  = (const float*)d_in[3];
    const float* cb1  = (const float*)d_in[4];
    const float* cw2  = (const float*)d_in[5];
    const float* cb2  = (const float*)d_in[6];
    const float* eps  = (const float*)d_in[7];
    const float* gsc  = (const float*)d_in[8];
    const float* gw   = (const float*)d_in[9];
    const float* gb   = (const float*)d_in[10];
    const float* pw1  = (const float*)d_in[11];
    const float* pb1  = (const float*)d_in[12];
    const float* pw2  = (const float*)d_in[13];
    const float* pb2  = (const float*)d_in[14];
    float* out = (float*)d_out;

    ushort_t* Xb   = (ushort_t*)d_ws;                       // N*128 bf16 — aliases Hn
    ushort_t* Hn   = Xb;
    ushort_t* Hraw = Xb + (size_t)NN * HIDD;                // N*128 bf16
    ushort_t* Wt   = Hraw + (size_t)NN * HIDD;              // 9*128*128 bf16
    float* msb     = (float*)(Wt + (size_t)9 * HIDD * HIDD);// G*128 f32
    float* invb    = msb + (size_t)GGG * HIDD;              // G*128 f32
    float* pooled  = invb + (size_t)GGG * HIDD;             // G*128 f32
    int* goff   = (int*)(pooled + (size_t)GGG * HIDD);      // G+1
    int* rowptr = goff + (GGG + 1);                         // N+1
    int* gcnt   = rowptr + (NN + 1);                        // NBK
    int* csr    = gcnt + NBK;                               // E
    unsigned int* bbuf = (unsigned int*)(csr + EE);         // NBK*CAPB

    hipMemsetAsync(gcnt, 0, NBK * sizeof(int), stream);
    k_pro<<<CVTB + 9 + 3 + ABLK, 256, 0, stream>>>(x, Xb, cw1, cw2, pw1, Wt, batch, goff, ei, gcnt, bbuf);
    k_csr<<<NBK, 256, 0, stream>>>(gcnt, bbuf, rowptr, csr);

    for (int l = 0; l < 3; l++) {
        const ushort_t* hin = (l == 0) ? Xb : Hn;
        ushort_t* Wt1 = Wt + (size_t)(l * 3 + 0) * HIDD * HIDD;
        ushort_t* Wt2 = Wt + (size_t)(l * 3 + 1) * HIDD * HIDD;
        ushort_t* Wtp = Wt + (size_t)(l * 3 + 2) * HIDD * HIDD;
        int grid = GBLK + (l > 0 ? OUTB : 0);
        k_gmlp<<<grid, 256, 0, stream>>>(hin, rowptr, csr, eps, l,
                                         Wt1, cb1 + l * HIDD, Wt2, cb2 + l * HIDD, Hraw,
                                         pooled, goff,
                                         pw2 + (size_t)(l - 1) * HIDD * TGTT, pb2 + (l - 1) * TGTT,
                                         out, l - 1);
        k_gstat<<<GGG, 512, 0, stream>>>(Hraw, goff, gsc + l * HIDD, gw + l * HIDD, msb, invb, pooled);
        k_projpool<<<GBLK, 256, 0, stream>>>(Hraw, batch, msb, invb, gb + l * HIDD,
                                             Wtp, pb1 + l * HIDD, Hn, pooled, (l < 2) ? 1 : 0);
    }
    k_out<<<OUTB, 256, 0, stream>>>(pooled, goff, pw2 + (size_t)2 * HIDD * TGTT, pb2 + 2 * TGTT, out, 2);
}